// Round 2
// baseline (199.174 us; speedup 1.0000x reference)
//
#include <hip/hip_runtime.h>

typedef __attribute__((ext_vector_type(8))) short short8;   // 8 bf16 (4 VGPRs)
typedef __attribute__((ext_vector_type(4))) float f32x4;    // MFMA accumulator

// pack two positive floats to bf16x2 with round-half-up: +0x8000 then take hi16
__device__ __forceinline__ unsigned pk_bf16(float lo, float hi) {
    const unsigned ul = __float_as_uint(lo) + 0x8000u;
    const unsigned uh = __float_as_uint(hi) + 0x8000u;
    return __builtin_amdgcn_perm(uh, ul, 0x07060302u);
}

// One wave = one batch. MFMA fragments loaded DIRECTLY from global memory:
// lane (t=lane&15, q=lane>>4) needs K-chunk [c*32+q*8 .. +7] of row t (A) and
// row idx_t (B) -- 16B-contiguous; the 4 q-lanes per row form one aligned
// 128B line. A (HBM) is software-pipelined 2 deep; B (phon, 256 KB, L2-hot)
// is loaded just-in-time under the exp chain. __launch_bounds__(256,8) caps
// VGPRs at 64 -> 8 blocks/CU -> whole grid resident in one pass.
// Chunk enumeration identical to prior versions -> bit-identical numerics.
__global__ __launch_bounds__(256, 8) void rhyme_kernel(
    const float* __restrict__ logits,   // [B,16,256]
    const int*   __restrict__ tidx,     // [B,16]
    const float* __restrict__ phon,     // [256,256], symmetric
    float*       __restrict__ out,      // [B]
    int B)
{
    __shared__ float sub_lds[4][16][17];
    __shared__ float p0s[4];            // first-char prob per wave

    const int lane = threadIdx.x & 63;
    const int wv   = threadIdx.x >> 6;
    int b = blockIdx.x * 4 + wv;
    if (b >= B) b = B - 1;              // duplicate work; stores gated later

    const int t = lane & 15;            // MFMA row / sub column owner
    const int q = lane >> 4;            // K quad

    const int idxt = tidx[b * 16 + t];  // lane's row of phon (B operand)
    const int idx0 = __shfl(idxt, 0);   // wave-uniform

    const float* ap = logits + (size_t)b * 4096 + t * 256 + q * 8;
    const float* bp = phon + (size_t)idxt * 256 + q * 8;

    union { short8 s; unsigned u[4]; } ones;
    ones.u[0] = ones.u[1] = ones.u[2] = ones.u[3] = 0x3F803F80u;  // bf16 1.0 x2

    f32x4 acc  = {0.f, 0.f, 0.f, 0.f};
    f32x4 accz = {0.f, 0.f, 0.f, 0.f};

    // prologue: stage A chunk 0 (HBM, long latency)
    float4 a0 = *(const float4*)(ap);
    float4 a1 = *(const float4*)(ap + 4);

    #pragma unroll
    for (int c = 0; c < 8; ++c) {
        // issue next A chunk before consuming current (2-deep pipeline)
        float4 na0, na1;
        if (c < 7) {
            na0 = *(const float4*)(ap + (c + 1) * 32);
            na1 = *(const float4*)(ap + (c + 1) * 32 + 4);
        }
        // B chunk just-in-time: L2-resident phon, latency hidden by exp chain
        const float4 b0 = *(const float4*)(bp + c * 32);
        const float4 b1 = *(const float4*)(bp + c * 32 + 4);

        union { short8 s; unsigned u[4]; } af, bf;
        af.u[0] = pk_bf16(__expf(a0.x), __expf(a0.y));
        af.u[1] = pk_bf16(__expf(a0.z), __expf(a0.w));
        af.u[2] = pk_bf16(__expf(a1.x), __expf(a1.y));
        af.u[3] = pk_bf16(__expf(a1.z), __expf(a1.w));
        bf.u[0] = pk_bf16(b0.x, b0.y);
        bf.u[1] = pk_bf16(b0.z, b0.w);
        bf.u[2] = pk_bf16(b1.x, b1.y);
        bf.u[3] = pk_bf16(b1.z, b1.w);

        // D[q*4+r][t]: acc = sub_unnorm, accz = softmax partition Z per row
        acc  = __builtin_amdgcn_mfma_f32_16x16x32_bf16(af.s, bf.s,   acc,  0, 0, 0);
        accz = __builtin_amdgcn_mfma_f32_16x16x32_bf16(af.s, ones.s, accz, 0, 0, 0);

        a0 = na0;
        a1 = na1;
    }

    // acc[r] = sub_unnorm[q*4+r][t], accz[r] = Z_{q*4+r}: same slot -> no shuffles
    #pragma unroll
    for (int r = 0; r < 4; ++r)
        sub_lds[wv][q * 4 + r][t] = acc[r] / accz[r];

    if (lane == 0) {
        // p0 = exp(logits[b][0][idx0]) / Z_0; lane 0 (t=0,q=0) holds Z_0=accz[0].
        // Row 0 is L2-hot; one 4B re-read is free.
        const float p0e = __expf(logits[(size_t)b * 4096 + idx0]);
        p0s[wv] = p0e / accz[0];
    }

    __syncthreads();
    if (wv != 0) return;                // wave 0 runs the block's 4 DPs merged

    // Anti-diagonal DP, 4 problems packed: group g = lane>>4, column j = (lane&15)+1.
    const int g  = lane >> 4;
    const int tl = lane & 15;
    const int j  = tl + 1;
    float P1 = 0.f, P2 = 0.f;
    #pragma unroll
    for (int d = 2; d <= 32; ++d) {
        const float lnv = __shfl_up(P1, 1);     // left  = cell(i, j-1)
        const float dgv = __shfl_up(P2, 1);     // diag  = cell(i-1, j-1)
        const int i = d - j;
        const float up   = (i == 1) ? 10.0f * (float)j : P1;
        const float left = (j == 1) ? 10.0f * (float)i : lnv;
        const float diag = (i == 1) ? 10.0f * (float)(j - 1)
                         : ((j == 1) ? 10.0f * (float)(i - 1) : dgv);
        int row = i - 1; row = row < 0 ? 0 : (row > 15 ? 15 : row);
        const float sv = sub_lds[g][row][tl];
        const float a  = up   + 10.0f;
        const float bc = left + 10.0f;
        const float cc = diag + sv;
        const float mn = fminf(a, fminf(bc, cc));
        const float sm = __expf(mn - a) + __expf(mn - bc) + __expf(mn - cc);
        const float val = mn - __logf(sm);
        const bool act = (i >= 1) && (i <= 16);
        P2 = act ? P1 : P2;
        P1 = act ? val : P1;
    }

    const int gb = blockIdx.x * 4 + g;
    if (tl == 15 && gb < B) {
        out[gb] = P1 + 10.0f * (1.0f - p0s[g]);  // dp(16,16) + 10*(1-p0)
    }
}

extern "C" void kernel_launch(void* const* d_in, const int* in_sizes, int n_in,
                              void* d_out, int out_size, void* d_ws, size_t ws_size,
                              hipStream_t stream) {
    const float* logits = (const float*)d_in[0];
    const int*   tidx   = (const int*)d_in[1];
    const float* phon   = (const float*)d_in[2];
    float* out = (float*)d_out;

    const int B = in_sizes[0] / (16 * 256);
    const int blocks = (B + 3) / 4;          // 4 waves = 4 batches per block
    hipLaunchKernelGGL(rhyme_kernel, dim3(blocks), dim3(256), 0, stream,
                       logits, tidx, phon, out, B);
}

// Round 3
// 196.432 us; speedup vs baseline: 1.0140x; 1.0140x over previous
//
#include <hip/hip_runtime.h>

typedef __attribute__((ext_vector_type(8))) short short8;   // 8 bf16 (4 VGPRs)
typedef __attribute__((ext_vector_type(4))) float f32x4;    // MFMA accumulator

// pack two positive floats to bf16x2 with round-half-up: +0x8000 then take hi16
__device__ __forceinline__ unsigned pk_bf16(float lo, float hi) {
    const unsigned ul = __float_as_uint(lo) + 0x8000u;
    const unsigned uh = __float_as_uint(hi) + 0x8000u;
    return __builtin_amdgcn_perm(uh, ul, 0x07060302u);
}

// One wave = one batch. MAX-MLP version: the whole A stream (16x16B/lane) and
// B stream (16x16B/lane) are hoisted into registers up front -- 32 independent
// loads in flight per lane (32 KB/wave) to cover the ~900-cycle HBM latency.
// tidx is issued first so the phon-address dependency hides under the A burst.
// No occupancy cap: pending-load data needs ~170 VGPRs (3 waves/SIMD is enough;
// BW per CU = in-flight bytes / latency, not wave count).
// Chunk enumeration/pack/MFMA order identical to prior versions -> bit-identical.
__global__ __launch_bounds__(256) void rhyme_kernel(
    const float* __restrict__ logits,   // [B,16,256]
    const int*   __restrict__ tidx,     // [B,16]
    const float* __restrict__ phon,     // [256,256], symmetric
    float*       __restrict__ out,      // [B]
    int B)
{
    __shared__ float sub_lds[4][16][17];
    __shared__ float p0s[4];            // first-char prob per wave

    const int lane = threadIdx.x & 63;
    const int wv   = threadIdx.x >> 6;
    int b = blockIdx.x * 4 + wv;
    if (b >= B) b = B - 1;              // duplicate work; stores gated later

    const int t = lane & 15;            // MFMA row / sub column owner
    const int q = lane >> 4;            // K quad

    // issue the index load FIRST: B addresses depend on it (~900 cy away)
    const int idxt = tidx[b * 16 + t];

    const float* ap = logits + (size_t)b * 4096 + t * 256 + q * 8;

    // hoist the entire A stream: 16 independent dwordx4 loads in flight
    float4 A[16];
    #pragma unroll
    for (int c = 0; c < 8; ++c) {
        A[2 * c]     = *(const float4*)(ap + c * 32);
        A[2 * c + 1] = *(const float4*)(ap + c * 32 + 4);
    }

    const int idx0 = __shfl(idxt, 0);   // wave-uniform
    const float* bp = phon + (size_t)idxt * 256 + q * 8;

    // hoist the B stream too (phon is L2-hot; adds in-flight depth for free)
    float4 Bv[16];
    #pragma unroll
    for (int c = 0; c < 8; ++c) {
        Bv[2 * c]     = *(const float4*)(bp + c * 32);
        Bv[2 * c + 1] = *(const float4*)(bp + c * 32 + 4);
    }

    union { short8 s; unsigned u[4]; } ones;
    ones.u[0] = ones.u[1] = ones.u[2] = ones.u[3] = 0x3F803F80u;  // bf16 1.0 x2

    f32x4 acc  = {0.f, 0.f, 0.f, 0.f};
    f32x4 accz = {0.f, 0.f, 0.f, 0.f};

    #pragma unroll
    for (int c = 0; c < 8; ++c) {
        const float4 a0 = A[2 * c],  a1 = A[2 * c + 1];
        const float4 b0 = Bv[2 * c], b1 = Bv[2 * c + 1];

        union { short8 s; unsigned u[4]; } af, bf;
        af.u[0] = pk_bf16(__expf(a0.x), __expf(a0.y));
        af.u[1] = pk_bf16(__expf(a0.z), __expf(a0.w));
        af.u[2] = pk_bf16(__expf(a1.x), __expf(a1.y));
        af.u[3] = pk_bf16(__expf(a1.z), __expf(a1.w));
        bf.u[0] = pk_bf16(b0.x, b0.y);
        bf.u[1] = pk_bf16(b0.z, b0.w);
        bf.u[2] = pk_bf16(b1.x, b1.y);
        bf.u[3] = pk_bf16(b1.z, b1.w);

        // D[q*4+r][t]: acc = sub_unnorm, accz = softmax partition Z per row
        acc  = __builtin_amdgcn_mfma_f32_16x16x32_bf16(af.s, bf.s,   acc,  0, 0, 0);
        accz = __builtin_amdgcn_mfma_f32_16x16x32_bf16(af.s, ones.s, accz, 0, 0, 0);
    }

    // acc[r] = sub_unnorm[q*4+r][t], accz[r] = Z_{q*4+r}: same slot -> no shuffles
    #pragma unroll
    for (int r = 0; r < 4; ++r)
        sub_lds[wv][q * 4 + r][t] = acc[r] / accz[r];

    if (lane == 0) {
        // p0 = exp(logits[b][0][idx0]) / Z_0; lane 0 (t=0,q=0) holds Z_0=accz[0].
        // Row 0 is cache-hot; one 4B re-read is free.
        const float p0e = __expf(logits[(size_t)b * 4096 + idx0]);
        p0s[wv] = p0e / accz[0];
    }

    __syncthreads();
    if (wv != 0) return;                // wave 0 runs the block's 4 DPs merged

    // Anti-diagonal DP, 4 problems packed: group g = lane>>4, column j = (lane&15)+1.
    const int g  = lane >> 4;
    const int tl = lane & 15;
    const int j  = tl + 1;
    float P1 = 0.f, P2 = 0.f;
    #pragma unroll
    for (int d = 2; d <= 32; ++d) {
        const float lnv = __shfl_up(P1, 1);     // left  = cell(i, j-1)
        const float dgv = __shfl_up(P2, 1);     // diag  = cell(i-1, j-1)
        const int i = d - j;
        const float up   = (i == 1) ? 10.0f * (float)j : P1;
        const float left = (j == 1) ? 10.0f * (float)i : lnv;
        const float diag = (i == 1) ? 10.0f * (float)(j - 1)
                         : ((j == 1) ? 10.0f * (float)(i - 1) : dgv);
        int row = i - 1; row = row < 0 ? 0 : (row > 15 ? 15 : row);
        const float sv = sub_lds[g][row][tl];
        const float a  = up   + 10.0f;
        const float bc = left + 10.0f;
        const float cc = diag + sv;
        const float mn = fminf(a, fminf(bc, cc));
        const float sm = __expf(mn - a) + __expf(mn - bc) + __expf(mn - cc);
        const float val = mn - __logf(sm);
        const bool act = (i >= 1) && (i <= 16);
        P2 = act ? P1 : P2;
        P1 = act ? val : P1;
    }

    const int gb = blockIdx.x * 4 + g;
    if (tl == 15 && gb < B) {
        out[gb] = P1 + 10.0f * (1.0f - p0s[g]);  // dp(16,16) + 10*(1-p0)
    }
}

extern "C" void kernel_launch(void* const* d_in, const int* in_sizes, int n_in,
                              void* d_out, int out_size, void* d_ws, size_t ws_size,
                              hipStream_t stream) {
    const float* logits = (const float*)d_in[0];
    const int*   tidx   = (const int*)d_in[1];
    const float* phon   = (const float*)d_in[2];
    float* out = (float*)d_out;

    const int B = in_sizes[0] / (16 * 256);
    const int blocks = (B + 3) / 4;          // 4 waves = 4 batches per block
    hipLaunchKernelGGL(rhyme_kernel, dim3(blocks), dim3(256), 0, stream,
                       logits, tidx, phon, out, B);
}